// Round 5
// baseline (1097.509 us; speedup 1.0000x reference)
//
#include <hip/hip_runtime.h>

// Problem dims (fixed by reference)
#define B_DIM 32
#define T_DIM 1024
#define I_DIM 4
#define H_DIM 2048
#define O_DIM 2
#define R_DIM 2
#define S_DIM 2
#define G_DIM 8

#define NOISE_STD 0.05f
#define ALPHA 0.2f
#define ONE_M_ALPHA (1.0f - ALPHA)
#define INV_H (1.0f / (float)H_DIM)

// Scan kernel: 512 threads = 8 waves = TWO independent batches x 4 waves.
// With round-robin wave->SIMD assignment (wave i -> SIMD i%4), waves 0-3
// (batch A) and 4-7 (batch B) pair up one-per-SIMD: batch A's dependency
// stalls overlap batch B's issue. grp = wave>>2 chooses exactly this pairing.
#define NT1 512
#define GSIZE 256               // threads per batch-group
#define EPT 8                   // h-elements per thread (2 float4 chunks)
#define PF_DEPTH 4              // noise prefetch ring depth (steps)

// Output kernel: full-GPU pass over stored trajectories.
#define NT2 256

// LDS small-weight layout offsets (floats)
#define WIW 0    // (I,S,G) = 64
#define MW  64   // (R,S,G) = 32
#define NW  96   // (R,S,G) = 32
#define WIB 128  // (I,S)   = 8
#define MB  136  // (R,S)   = 4
#define NB  140  // (R,S)   = 4
#define H0W 144  // (S,G)   = 16
#define WTOT 160

__device__ __forceinline__ float f4get(const float4 v, int e) {
    return e == 0 ? v.x : e == 1 ? v.y : e == 2 ? v.z : v.w;
}

// tanh(x) = 1 - 2/(e^{2x}+1) with raw v_exp/v_rcp: 5 insts, 2 trans,
// no IEEE-div expansion, no VCC serialization.
__device__ __forceinline__ float fast_tanh(float x) {
    float e2;
    float t = x * 2.88539008178f;  // 2*log2(e): e^{2x} = 2^t
    asm("v_exp_f32 %0, %1" : "=v"(e2) : "v"(t));
    float r;
    asm("v_rcp_f32 %0, %1" : "=v"(r) : "v"(e2 + 1.0f));
    return fmaf(-2.0f, r, 1.0f);
}

// LDS-only barrier: orders LDS ops across the workgroup WITHOUT the
// s_waitcnt vmcnt(0) drain that __syncthreads() emits. Keeps the noise
// prefetch ring and trajectory stores in flight across steps.
__device__ __forceinline__ void lds_barrier() {
    asm volatile("s_waitcnt lgkmcnt(0)" ::: "memory");
    __builtin_amdgcn_s_barrier();
    asm volatile("" ::: "memory");  // fence: no LDS op hoisted above the barrier
}

// Full-wave (64-lane) sum via DPP — pure VALU, no LDS pipe. Result valid in lane 63.
#define DPP_ADD_F(x, ctrl) \
    x += __int_as_float(__builtin_amdgcn_update_dpp(0, __float_as_int(x), (ctrl), 0xf, 0xf, true))

__device__ __forceinline__ float wave_reduce63(float x) {
    DPP_ADD_F(x, 0x111);  // row_shr:1
    DPP_ADD_F(x, 0x112);  // row_shr:2
    DPP_ADD_F(x, 0x114);  // row_shr:4
    DPP_ADD_F(x, 0x118);  // row_shr:8  -> lane 15 of each row has row sum
    DPP_ADD_F(x, 0x142);  // row_bcast:15 -> lane 31 has lanes 0-31, lane 63 has 32-63
    DPP_ADD_F(x, 0x143);  // row_bcast:31 -> lane 63 has full sum
    return x;
}

__global__ __launch_bounds__(NT1, 1) void rnn_kernel(
    const float* __restrict__ input,   // (B,T,I)
    const float* __restrict__ noise,   // (B,T,H)
    const float* __restrict__ gb,      // (G,H)
    const float* __restrict__ sup,     // (S,H)
    const float* __restrict__ wi_w,    // (I,S,G)
    const float* __restrict__ m_w,     // (R,S,G)
    const float* __restrict__ n_w,     // (R,S,G)
    const float* __restrict__ wi_b,    // (I,S)
    const float* __restrict__ m_b,     // (R,S)
    const float* __restrict__ n_b,     // (R,S)
    const float* __restrict__ h0_w,    // (S,G)
    float* __restrict__ out)           // (B,T,O) then (B,T,H), flat
{
    const int tid   = threadIdx.x;
    const int wave  = tid >> 6;
    const int lane  = tid & 63;
    const int grp   = wave >> 2;          // 0 or 1: which batch this wave serves
    const int gtid  = tid & (GSIZE - 1);  // thread index within the group
    const int b     = blockIdx.x * 2 + grp;

    __shared__ float s_input[2][T_DIM * I_DIM];          // 2 x 16 KB
    __shared__ __align__(16) float2 s_part[2][2][4];     // [buf][grp][wave]
    __shared__ float s_w[WTOT];

    // ---- stage both batches' inputs and the small weights into LDS ----
    {
        const float4* inp4 = (const float4*)(input + (size_t)b * (T_DIM * I_DIM));
        float4* sIn4 = (float4*)s_input[grp];
        #pragma unroll
        for (int k = gtid; k < T_DIM * I_DIM / 4; k += GSIZE) sIn4[k] = inp4[k];

        if (tid < 64)       s_w[tid] = wi_w[tid];
        else if (tid < 96)  s_w[tid] = m_w[tid - 64];
        else if (tid < 128) s_w[tid] = n_w[tid - 96];
        else if (tid < 136) s_w[tid] = wi_b[tid - 128];
        else if (tid < 140) s_w[tid] = m_b[tid - 136];
        else if (tid < 144) s_w[tid] = n_b[tid - 140];
        else if (tid < 160) s_w[tid] = h0_w[tid - 144];
    }
    __syncthreads();

    // Each group-thread owns two contiguous float4 chunks of its batch's H:
    //   chunk 0: floats [4*gtid .. +3]         (group covers 0..1023)
    //   chunk 1: floats [1024+4*gtid .. +3]    (group covers 1024..2047)
    const int h_off0 = 4 * gtid;
    const int h_off1 = 1024 + 4 * gtid;

    float wiP[EPT][I_DIM], mP[EPT][R_DIM], nP[EPT][R_DIM];
    float h_reg[EPT], g_reg[EPT];

    #pragma unroll
    for (int c = 0; c < 2; ++c) {
        const int hb = c == 0 ? h_off0 : h_off1;
        float4 gbv[G_DIM];
        #pragma unroll
        for (int g = 0; g < G_DIM; ++g)
            gbv[g] = *(const float4*)(gb + (size_t)g * H_DIM + hb);
        float4 supv[S_DIM];
        #pragma unroll
        for (int s = 0; s < S_DIM; ++s)
            supv[s] = *(const float4*)(sup + (size_t)s * H_DIM + hb);

        #pragma unroll
        for (int j = 0; j < 4; ++j) {
            const int e = c * 4 + j;
            float gcol[G_DIM];
            #pragma unroll
            for (int g = 0; g < G_DIM; ++g) gcol[g] = f4get(gbv[g], j);

            #pragma unroll
            for (int i = 0; i < I_DIM; ++i) wiP[e][i] = 0.0f;
            #pragma unroll
            for (int r = 0; r < R_DIM; ++r) { mP[e][r] = 0.0f; nP[e][r] = 0.0f; }
            float h0v = 0.0f;

            #pragma unroll
            for (int s = 0; s < S_DIM; ++s) {
                float sv = f4get(supv[s], j);
                #pragma unroll
                for (int i = 0; i < I_DIM; ++i) {
                    float d = 0.0f;
                    #pragma unroll
                    for (int g = 0; g < G_DIM; ++g)
                        d = fmaf(s_w[WIW + (i * S_DIM + s) * G_DIM + g], gcol[g], d);
                    wiP[e][i] = fmaf(sv, d + s_w[WIB + i * S_DIM + s], wiP[e][i]);
                }
                #pragma unroll
                for (int r = 0; r < R_DIM; ++r) {
                    float dm = 0.0f, dn = 0.0f;
                    #pragma unroll
                    for (int g = 0; g < G_DIM; ++g) {
                        dm = fmaf(s_w[MW + (r * S_DIM + s) * G_DIM + g], gcol[g], dm);
                        dn = fmaf(s_w[NW + (r * S_DIM + s) * G_DIM + g], gcol[g], dn);
                    }
                    mP[e][r] = fmaf(sv, dm + s_w[MB + r * S_DIM + s], mP[e][r]);
                    nP[e][r] = fmaf(sv, dn + s_w[NB + r * S_DIM + s], nP[e][r]);
                }
                {
                    float d = 0.0f;
                    #pragma unroll
                    for (int g = 0; g < G_DIM; ++g)
                        d = fmaf(s_w[H0W + s * G_DIM + g], gcol[g], d);
                    h0v = fmaf(sv, d, h0v);
                }
            }
            h_reg[e] = h0v;
            g_reg[e] = fast_tanh(h0v);
        }
    }

    // Fold constants: nP *= 1/H (kappa comes out of the reduce pre-scaled);
    // wiP, mP *= ALPHA (h-update becomes h = (1-A)h + STD*nz + u' + rec').
    #pragma unroll
    for (int e = 0; e < EPT; ++e) {
        nP[e][0] *= INV_H;  nP[e][1] *= INV_H;
        mP[e][0] *= ALPHA;  mP[e][1] *= ALPHA;
        #pragma unroll
        for (int i = 0; i < I_DIM; ++i) wiP[e][i] *= ALPHA;
    }

    // ---- noise prefetch ring ----
    const float4* noi4 = (const float4*)(noise + (size_t)b * T_DIM * H_DIM);
    float4* traj4 = (float4*)(out + (size_t)B_DIM * T_DIM * O_DIM + (size_t)b * T_DIM * H_DIM);
    const int f4_0 = gtid;        // chunk-0 float4 index within a step's 512
    const int f4_1 = 256 + gtid;  // chunk-1

    float4 ring[PF_DEPTH][2];
    #pragma unroll
    for (int d = 0; d < PF_DEPTH; ++d) {
        ring[d][0] = noi4[(size_t)d * 512 + f4_0];
        ring[d][1] = noi4[(size_t)d * 512 + f4_1];
    }

    // ---- main scan (kappa only; output pass is a separate kernel) ----
    #pragma unroll 4
    for (int t = 0; t < T_DIM; ++t) {
        const int buf = t & 1;
        const int slot = t & (PF_DEPTH - 1);

        // consume ring slot, refill with t+PF_DEPTH (in flight across barrier)
        float4 nz0 = ring[slot][0];
        float4 nz1 = ring[slot][1];
        {
            int tp = t + PF_DEPTH; if (tp > T_DIM - 1) tp = T_DIM - 1;
            ring[slot][0] = noi4[(size_t)tp * 512 + f4_0];
            ring[slot][1] = noi4[(size_t)tp * 512 + f4_1];
        }
        const float4 uin = *(const float4*)(&s_input[grp][t * I_DIM]);

        // kappa partials (nP pre-scaled by 1/H)
        float p0 = 0.f, p1 = 0.f;
        #pragma unroll
        for (int e = 0; e < EPT; ++e) {
            float g = g_reg[e];
            p0 = fmaf(g, nP[e][0], p0);
            p1 = fmaf(g, nP[e][1], p1);
        }
        p0 = wave_reduce63(p0);
        p1 = wave_reduce63(p1);
        if (lane == 63) s_part[buf][grp][wave & 3] = make_float2(p0, p1);
        lds_barrier();   // LDS-only: no vmcnt drain

        // cross-wave sum within this group: 4 float2 = two float4 reads
        const float4* sp = (const float4*)&s_part[buf][grp][0];
        float4 q0 = sp[0];   // waves 0,1
        float4 q1 = sp[1];   // waves 2,3
        const float k0 = (q0.x + q0.z) + (q1.x + q1.z);
        const float k1 = (q0.y + q0.w) + (q1.y + q1.w);

        float4 tr0, tr1;
        #pragma unroll
        for (int e = 0; e < EPT; ++e) {
            float u = uin.x * wiP[e][0];               // wiP pre-scaled by ALPHA
            u = fmaf(uin.y, wiP[e][1], u);
            u = fmaf(uin.z, wiP[e][2], u);
            u = fmaf(uin.w, wiP[e][3], u);
            float rec = k0 * mP[e][0];                 // mP pre-scaled by ALPHA
            rec = fmaf(k1, mP[e][1], rec);
            float nzv = e < 4 ? f4get(nz0, e) : f4get(nz1, e - 4);
            float base = fmaf(NOISE_STD, nzv, u + rec);
            float h = fmaf(ONE_M_ALPHA, h_reg[e], base);
            h_reg[e] = h;
            g_reg[e] = fast_tanh(h);
            float* trp = e < 4 ? (float*)&tr0 : (float*)&tr1;
            trp[e & 3] = h;
        }
        traj4[(size_t)t * 512 + f4_0] = tr0;
        traj4[(size_t)t * 512 + f4_1] = tr1;
    }
}

// Output pass: out[b,t,:] = (1/H) * tanh(traj[b,t,:]) @ wo.
// traj holds exactly the h values the scan produced, so this matches the
// reference's out_t = tanh(h_t) @ wo / H. Full-GPU parallel over (b, t-chunks).
__global__ __launch_bounds__(NT2, 1) void out_kernel(
    const float* __restrict__ gb,      // (G,H)
    const float* __restrict__ sup,     // (S,H)
    const float* __restrict__ wo_w,    // (O,S,G)
    float* __restrict__ out)
{
    const int bid  = blockIdx.x;
    const int b    = bid >> 6;          // 64 t-chunks per batch
    const int t0   = (bid & 63) << 4;   // 16 rows per block
    const int tid  = threadIdx.x;
    const int wave = tid >> 6;
    const int lane = tid & 63;

    __shared__ __align__(16) float2 s_part[2][4];

    const float* traj = out + (size_t)B_DIM * T_DIM * O_DIM + (size_t)b * T_DIM * H_DIM;

    // build this thread's wo slice (same two-chunk H layout as the scan)
    float woP[EPT][O_DIM];
    #pragma unroll
    for (int c = 0; c < 2; ++c) {
        const int hb = c == 0 ? 4 * tid : 1024 + 4 * tid;
        float4 gbv[G_DIM];
        #pragma unroll
        for (int g = 0; g < G_DIM; ++g)
            gbv[g] = *(const float4*)(gb + (size_t)g * H_DIM + hb);
        float4 supv[S_DIM];
        #pragma unroll
        for (int s = 0; s < S_DIM; ++s)
            supv[s] = *(const float4*)(sup + (size_t)s * H_DIM + hb);

        #pragma unroll
        for (int j = 0; j < 4; ++j) {
            const int e = c * 4 + j;
            float gcol[G_DIM];
            #pragma unroll
            for (int g = 0; g < G_DIM; ++g) gcol[g] = f4get(gbv[g], j);
            float w0 = 0.f, w1 = 0.f;
            #pragma unroll
            for (int s = 0; s < S_DIM; ++s) {
                float sv = f4get(supv[s], j);
                float d0 = 0.f, d1 = 0.f;
                #pragma unroll
                for (int g = 0; g < G_DIM; ++g) {
                    d0 = fmaf(wo_w[(0 * S_DIM + s) * G_DIM + g], gcol[g], d0);
                    d1 = fmaf(wo_w[(1 * S_DIM + s) * G_DIM + g], gcol[g], d1);
                }
                w0 = fmaf(sv, d0, w0);
                w1 = fmaf(sv, d1, w1);
            }
            woP[e][0] = w0 * INV_H;
            woP[e][1] = w1 * INV_H;
        }
    }

    for (int tt = 0; tt < 16; ++tt) {
        const int t = t0 + tt;
        const float4 a0 = *(const float4*)(traj + (size_t)t * H_DIM + 4 * tid);
        const float4 a1 = *(const float4*)(traj + (size_t)t * H_DIM + 1024 + 4 * tid);
        float p0 = 0.f, p1 = 0.f;
        #pragma unroll
        for (int e = 0; e < EPT; ++e) {
            float h = e < 4 ? f4get(a0, e) : f4get(a1, e - 4);
            float g = fast_tanh(h);
            p0 = fmaf(g, woP[e][0], p0);
            p1 = fmaf(g, woP[e][1], p1);
        }
        p0 = wave_reduce63(p0);
        p1 = wave_reduce63(p1);
        if (lane == 63) s_part[tt & 1][wave] = make_float2(p0, p1);
        __syncthreads();
        if (tid == 0) {
            float x = 0.f, y = 0.f;
            #pragma unroll
            for (int w = 0; w < 4; ++w) { x += s_part[tt & 1][w].x; y += s_part[tt & 1][w].y; }
            *(float2*)(out + ((size_t)b * T_DIM + t) * O_DIM) = make_float2(x, y);
        }
    }
}

extern "C" void kernel_launch(void* const* d_in, const int* in_sizes, int n_in,
                              void* d_out, int out_size, void* d_ws, size_t ws_size,
                              hipStream_t stream) {
    rnn_kernel<<<B_DIM / 2, NT1, 0, stream>>>(
        (const float*)d_in[0],  // input
        (const float*)d_in[1],  // noise
        (const float*)d_in[2],  // gaussian_basis
        (const float*)d_in[3],  // supports
        (const float*)d_in[4],  // wi_weights
        (const float*)d_in[5],  // m_weights
        (const float*)d_in[6],  // n_weights
        (const float*)d_in[8],  // wi_biases
        (const float*)d_in[9],  // m_biases
        (const float*)d_in[10], // n_biases
        (const float*)d_in[11], // h0_weights
        (float*)d_out);
    out_kernel<<<B_DIM * 64, NT2, 0, stream>>>(
        (const float*)d_in[2],  // gaussian_basis
        (const float*)d_in[3],  // supports
        (const float*)d_in[7],  // wo_weights
        (float*)d_out);
}